// Round 13
// baseline (151.785 us; speedup 1.0000x reference)
//
#include <hip/hip_runtime.h>
#include <cstdint>

typedef unsigned long long ull;

#define N_BOX 8192
#define N_WORDS 128   // 8192 / 64
#define CH 512        // chunk size
#define WPC 8         // words per chunk

// ---------------- workspace layout ----------------
// TB (distance>=2 transposed col-blocks): 53760 rows * 64 B = 3,440,640 @ 0
// TC (superdiagonal transposed blocks):   15 * 32 KB        =   491,520 @ 3,440,640
// TD (per-chunk diagonal tables):         16 * 32 KB        =   524,288 @ 3,932,160
// boxes4 : 131072 @ 4,456,448
// scores : 32768  @ 4,587,520
// rank   : 32768  @ 4,620,288
// maxc   : 4      @ 4,653,056
#define OFF_TB     0
#define OFF_TC     3440640
#define OFF_TD     3932160
#define OFF_BOXES  4456448
#define OFF_SCORES 4587520
#define OFF_RANK   4620288
#define OFF_MAXC   4653056

// TB rows for source chunk c' cover j >= CH*(c'+2): 7168-512c' rows (c'=0..13)
__device__ __forceinline__ int rows_before2(int c) {
    return 7424 * c - 256 * c * c;   // sum_{c'<c} (7168 - 512c')
}

__device__ __forceinline__ ull make_key(float s, int idx) {
    // positive floats: bit pattern is order-preserving. Reversed index in the
    // low 13 bits reproduces stable argsort(-conf): equal conf -> lower index first.
    return (((ull)__float_as_uint(s)) << 13) | (ull)(8191 - idx);
}

__device__ __forceinline__ float box_area(float4 b) {
    return __fmul_rn(__fsub_rn(b.z, b.x), __fsub_rn(b.w, b.y));
}

// exact replica of reference IoU rounding (_rn ops block FMA contraction); symmetric.
__device__ __forceinline__ bool iou_gt_half(float4 a, float aarea, float4 b, float barea) {
    float ix1 = fmaxf(a.x, b.x);
    float iy1 = fmaxf(a.y, b.y);
    float ix2 = fminf(a.z, b.z);
    float iy2 = fminf(a.w, b.w);
    float iw = fmaxf(__fsub_rn(ix2, ix1), 0.0f);
    float ih = fmaxf(__fsub_rn(iy2, iy1), 0.0f);
    float inter = __fmul_rn(iw, ih);
    float uni = __fsub_rn(__fadd_rn(aarea, barea), inter);
    float iou = __fdiv_rn(inter, fmaxf(uni, 1e-9f));
    return iou > 0.5f;
}

// K1: global conf max via int-bits atomicMax (conf>=0; 0xAA.. poison is negative
// int so no pre-init needed); each block zeroes its rank slice.
__global__ __launch_bounds__(256) void k1_max_zero(const float* __restrict__ in,
                                                   int* __restrict__ maxci,
                                                   int* __restrict__ rank) {
    int t = threadIdx.x;
    int i = blockIdx.x * 256 + t;
    float c = in[i * 5 + 4];
    for (int off = 32; off; off >>= 1) c = fmaxf(c, __shfl_down(c, off));
    __shared__ float wm[4];
    if ((t & 63) == 0) wm[t >> 6] = c;
    __syncthreads();
    if (t == 0) {
        float m = fmaxf(fmaxf(wm[0], wm[1]), fmaxf(wm[2], wm[3]));
        atomicMax(maxci, __float_as_int(m));
    }
    rank[i] = 0;
}

// K2: rank[i] = #{ j : key_j > key_i }  (descending sort position, stable ties)
__global__ __launch_bounds__(256) void k2_rank(const float* __restrict__ in,
                                               const float* __restrict__ maxc_p,
                                               int* __restrict__ rank) {
    __shared__ ull keys[1024];
    int t = threadIdx.x;
    int bx = blockIdx.x;
    int it = bx & 31;       // i tile: 256 boxes
    int jt = bx >> 5;       // j tile: 1024 boxes (8 tiles)
    float maxc = *maxc_p;
    for (int r = 0; r < 4; ++r) {
        int j = jt * 1024 + r * 256 + t;
        float s = __fdiv_rn(in[j * 5 + 4], maxc);
        keys[r * 256 + t] = make_key(s, j);
    }
    __syncthreads();
    int i = it * 256 + t;
    ull ki = make_key(__fdiv_rn(in[i * 5 + 4], maxc), i);
    int cnt = 0;
    #pragma unroll 8
    for (int k = 0; k < 1024; ++k) cnt += (keys[k] > ki) ? 1 : 0;
    atomicAdd(&rank[i], cnt);
}

// K3: scatter boxes/scores into sorted order
__global__ __launch_bounds__(256) void k3_scatter(const float* __restrict__ in,
                                                  const int* __restrict__ rank,
                                                  const float* __restrict__ maxc_p,
                                                  float4* __restrict__ boxes4,
                                                  float* __restrict__ scores) {
    int i = blockIdx.x * 256 + threadIdx.x;
    float cx = in[i * 5 + 0];
    float cy = in[i * 5 + 1];
    float w  = in[i * 5 + 2];
    float h  = in[i * 5 + 3];
    float c  = in[i * 5 + 4];
    float maxc = *maxc_p;
    float s = __fdiv_rn(c, maxc);
    int r = rank[i];
    float4 b;
    b.x = __fsub_rn(cx, __fmul_rn(w, 0.5f));
    b.y = __fsub_rn(cy, __fmul_rn(h, 0.5f));
    b.z = __fadd_rn(cx, __fmul_rn(w, 0.5f));
    b.w = __fadd_rn(cy, __fmul_rn(h, 0.5f));
    boxes4[r] = b;
    scores[r] = s;
}

// K4: build suppression bit tables.
//  bid <  1680        : TB — source chunk c, target j >= CH*(c+2), 32 j x 8 w tiles
//  1680 <= bid < 1920 : TC — source chunk c (0..14), target chunk c+1; transposed
//                       TC[c][w][jl] = word-w boxes of chunk c suppressing jl
//  bid >= 1920        : TD — diagonal, TD[c][w][jl], pre-masked to suppressors < jl
__global__ __launch_bounds__(256) void k4_build(const float4* __restrict__ boxes4,
                                                const float* __restrict__ scores,
                                                ull* __restrict__ TB,
                                                ull* __restrict__ TC,
                                                ull* __restrict__ TD) {
    __shared__ float4 sb[CH];
    __shared__ float sa[CH];
    int bid = blockIdx.x;
    int t = threadIdx.x;
    int c;
    int mode;   // 0=TB, 1=TC, 2=TD
    int j0;     // TB: global j tile start; TC/TD: local jl tile start
    if (bid >= 1920) {
        mode = 2;
        int d = bid - 1920;
        c = d >> 4;
        j0 = (d & 15) * 32;
    } else if (bid >= 1680) {
        mode = 1;
        int d = bid - 1680;
        c = d >> 4;          // 0..14
        j0 = (d & 15) * 32;
    } else {
        mode = 0;
        c = 0;
        int rem = bid;
        while (rem >= 224 - 16 * c) { rem -= 224 - 16 * c; ++c; }
        j0 = CH * (c + 2) + rem * 32;
    }
    if (scores[c * CH] < 0.5f) return;               // source chunk never a suppressor
    if (mode == 0 && scores[j0] < 0.5f) return;      // j-tile never alive (desc scores)

    for (int i = t; i < CH; i += 256) {
        float4 b = boxes4[c * CH + i];
        sb[i] = b;
        sa[i] = box_area(b);
    }
    __syncthreads();

    int w = t & 7;
    int r = t >> 3;          // 0..31 local row
    if (mode == 2) {
        int jl = j0 + r;
        float4 me = sb[jl];
        float ma = sa[jl];
        int wj = jl >> 6;
        int lim = (w < wj) ? 64 : ((w == wj) ? (jl & 63) : 0);
        ull bits = 0;
        for (int k = 0; k < lim; ++k)
            if (iou_gt_half(sb[w * 64 + k], sa[w * 64 + k], me, ma)) bits |= 1ull << k;
        TD[c * 4096 + w * 512 + jl] = bits;
    } else if (mode == 1) {
        int jl = j0 + r;
        int j = CH * (c + 1) + jl;
        float4 me = boxes4[j];
        float ma = box_area(me);
        ull bits = 0;
        for (int k = 0; k < 64; ++k)
            if (iou_gt_half(sb[w * 64 + k], sa[w * 64 + k], me, ma)) bits |= 1ull << k;
        TC[c * 4096 + w * 512 + jl] = bits;
    } else {
        int j = j0 + r;
        float4 me = boxes4[j];
        float ma = box_area(me);
        ull bits = 0;
        for (int k = 0; k < 64; ++k)
            if (iou_gt_half(sb[w * 64 + k], sa[w * 64 + k], me, ma)) bits |= 1ull << k;
        TB[(size_t)(rows_before2(c) + (j - CH * (c + 2))) * WPC + w] = bits;
    }
}

// K5: chunk-sequential greedy NMS, one 1024-thread block, ONE barrier per chunk.
//  Wave 0     : TC-ballot apply of kept[c-1] -> chunk c (LDS), then scan chunk c.
//               (R11 form — direct ballots, results live in SGPRs; R12's VALU-fold
//               accumulator variant regressed 43->54 us.)
//  Waves 1-7  : deferred TB apply of kept[c-1] -> chunks >= c+1, two-phase:
//               (1) LDS-only alive scan into a bitmask, (2) QUAD row loads
//               (4 rows in flight -> fewer serialized L2/L3 round-trips).
//  Waves 8-11 : prefetch TD[c+1]; waves 12-15: prefetch TC[c].
__global__ __launch_bounds__(1024) void k5_nms(const float4* __restrict__ boxes4,
                                               const float* __restrict__ scores,
                                               const ull* __restrict__ TBg,
                                               const ull* __restrict__ TCg,
                                               const ull* __restrict__ TDg,
                                               float* __restrict__ out) {
    __shared__ ull TDb[2][CH * WPC];            // 2 x 32 KB
    __shared__ ull TCb[2][CH * WPC];            // 2 x 32 KB
    __shared__ unsigned amask32[2 * N_WORDS];
    __shared__ ull keptbuf[2][WPC];
    __shared__ int svb;
    int t = threadIdx.x;
    int lane = t & 63;
    int wave = t >> 6;

    // ---- vb from sorted-score prefix ----
    if (t == 0) svb = 0;
    __syncthreads();
    {
        int cnt = 0;
        #pragma unroll
        for (int k = 0; k < 8; ++k) cnt += (scores[k * 1024 + t] >= 0.5f) ? 1 : 0;
        for (int off = 32; off; off >>= 1) cnt += __shfl_down(cnt, off);
        if (lane == 0) atomicAdd(&svb, cnt);
    }
    // ---- stage chunk-0 TD while the add settles ----
    for (int i2 = t; i2 < CH * WPC; i2 += 1024) TDb[0][i2] = TDg[i2];
    if (t < WPC) { keptbuf[0][t] = 0; keptbuf[1][t] = 0; }
    __syncthreads();
    int vb = svb;

    // ---- alive mask from prefix ----
    if (t < 2 * N_WORDS) {
        int n = vb - t * 32;
        amask32[t] = (n >= 32) ? 0xffffffffu : ((n <= 0) ? 0u : ((1u << n) - 1u));
    }
    __syncthreads();

    int nchv = (vb + CH - 1) / CH;
    for (int c = 0; c < nchv; ++c) {
        int cur = c & 1;
        if (wave == 0) {
            // ---- load alive words of chunk c ----
            ull alive[WPC];
            #pragma unroll
            for (int w = 0; w < WPC; ++w)
                alive[w] = (ull)amask32[c * 16 + 2 * w] |
                           ((ull)amask32[c * 16 + 2 * w + 1] << 32);
            // ---- TC-ballot apply: kept[c-1] -> chunk c ----
            if (c > 0) {
                const ull* kb = keptbuf[(c - 1) & 1];
                const ull* TCc = TCb[cur];
                #pragma unroll
                for (int w = 0; w < WPC; ++w) {
                    ull kw = kb[w];
                    if (!kw) continue;
                    ull Tc2[WPC];
                    #pragma unroll
                    for (int v = 0; v < WPC; ++v)
                        Tc2[v] = TCc[w * 512 + v * 64 + lane];   // pipelined preload
                    #pragma unroll
                    for (int v = 0; v < WPC; ++v)
                        alive[v] &= ~__ballot((Tc2[v] & kw) != 0);
                }
            }
            // ---- scan chunk c (TD-col preload -> ballot fixpoint -> applies) ----
            const ull* T = TDb[cur];
            #pragma unroll
            for (int w = 0; w < WPC; ++w) {
                ull word = alive[w];
                if (!word) continue;
                ull Tc[WPC];
                #pragma unroll
                for (int j = 0; j < WPC; ++j)
                    if (j >= w) Tc[j] = T[w * 512 + j * 64 + lane];
                ull td = Tc[w];
                ull a2 = word, kept = 0;
                while (a2 & ~kept) {
                    bool al = (a2 >> lane) & 1;
                    bool kp = (kept >> lane) & 1;
                    ull nk = __ballot(al && !kp && ((td & a2) == 0));
                    ull nd = __ballot(al && !kp && ((td & kept) != 0));
                    kept |= nk;
                    a2 &= ~nd;
                }
                alive[w] = kept;
                #pragma unroll
                for (int j = 0; j < WPC; ++j) {
                    if (j <= w) continue;
                    if (!alive[j]) continue;
                    alive[j] &= ~__ballot((Tc[j] & kept) != 0);
                }
            }
            if (lane == 0) {
                #pragma unroll
                for (int w = 0; w < WPC; ++w) {
                    amask32[c * 16 + 2 * w]     = (unsigned)alive[w];
                    amask32[c * 16 + 2 * w + 1] = (unsigned)(alive[w] >> 32);
                    keptbuf[c & 1][w] = alive[w];
                }
            }
        } else if (wave < 8) {
            // ---- deferred TB apply: kept[c-1] -> j in chunks >= c+1 ----
            if (c > 0 && c - 1 <= 13) {
                const ull* kb = keptbuf[(c - 1) & 1];
                ull kw[WPC];
                ull anyk = 0;
                #pragma unroll
                for (int k = 0; k < WPC; ++k) { kw[k] = kb[k]; anyk |= kw[k]; }
                if (anyk) {
                    const ull* TBc = TBg + (size_t)rows_before2(c - 1) * WPC;
                    int jbase = CH * (c + 1);    // TB rows of chunk c-1 start here
                    int base = jbase + (t - 64);
                    // phase 1: LDS-only alive scan -> bitmask (pipelined reads)
                    unsigned am = 0;
                    int k = 0;
                    for (int j = base; j < vb; j += 448, ++k)
                        am |= (((amask32[j >> 5] >> (j & 31)) & 1u) << k);
                    // phase 2: quad row loads (4 rows in flight)
                    while (am) {
                        int b1 = __builtin_ctz(am);
                        am &= am - 1;
                        int b2 = am ? __builtin_ctz(am) : b1;
                        bool h2 = (am != 0);
                        if (h2) am &= am - 1;
                        int b3 = am ? __builtin_ctz(am) : b1;
                        bool h3 = (am != 0);
                        if (h3) am &= am - 1;
                        int b4 = am ? __builtin_ctz(am) : b1;
                        bool h4 = (am != 0);
                        if (h4) am &= am - 1;
                        int j1 = base + b1 * 448;
                        int j2 = base + b2 * 448;
                        int j3 = base + b3 * 448;
                        int j4 = base + b4 * 448;
                        const ull* r1 = TBc + (size_t)(j1 - jbase) * WPC;
                        const ull* r2 = TBc + (size_t)(j2 - jbase) * WPC;
                        const ull* r3 = TBc + (size_t)(j3 - jbase) * WPC;
                        const ull* r4 = TBc + (size_t)(j4 - jbase) * WPC;
                        ull a1 = 0, a2v = 0, a3 = 0, a4 = 0;
                        #pragma unroll
                        for (int q = 0; q < WPC; ++q) a1 |= r1[q] & kw[q];
                        #pragma unroll
                        for (int q = 0; q < WPC; ++q) a2v |= r2[q] & kw[q];
                        #pragma unroll
                        for (int q = 0; q < WPC; ++q) a3 |= r3[q] & kw[q];
                        #pragma unroll
                        for (int q = 0; q < WPC; ++q) a4 |= r4[q] & kw[q];
                        if (a1) atomicAnd(&amask32[j1 >> 5], ~(1u << (j1 & 31)));
                        if (h2 && a2v) atomicAnd(&amask32[j2 >> 5], ~(1u << (j2 & 31)));
                        if (h3 && a3) atomicAnd(&amask32[j3 >> 5], ~(1u << (j3 & 31)));
                        if (h4 && a4) atomicAnd(&amask32[j4 >> 5], ~(1u << (j4 & 31)));
                    }
                }
            }
        } else if (wave < 12) {
            // ---- prefetch TD[c+1] ----
            if (c + 1 < nchv) {
                const ull* src = TDg + (c + 1) * CH * WPC;
                ull* dst = TDb[cur ^ 1];
                for (int i2 = t - 512; i2 < CH * WPC; i2 += 256) dst[i2] = src[i2];
            }
        } else {
            // ---- prefetch TC[c] (consumed at iteration c+1) ----
            if (c + 1 < nchv) {
                const ull* src = TCg + c * CH * WPC;
                ull* dst = TCb[cur ^ 1];
                for (int i2 = t - 768; i2 < CH * WPC; i2 += 256) dst[i2] = src[i2];
            }
        }
        __syncthreads();
    }

    // ---- epilogue: write all 8192 output rows ----
    #pragma unroll
    for (int rr = 0; rr < 8; ++rr) {
        int j = t * 8 + rr;
        bool kept = (amask32[j >> 5] >> (j & 31)) & 1u;
        float4 b = boxes4[j];
        float s = scores[j];
        out[j * 5 + 0] = kept ? b.x : 0.0f;
        out[j * 5 + 1] = kept ? b.y : 0.0f;
        out[j * 5 + 2] = kept ? b.z : 0.0f;
        out[j * 5 + 3] = kept ? b.w : 0.0f;
        out[j * 5 + 4] = kept ? s   : 0.0f;
    }
}

extern "C" void kernel_launch(void* const* d_in, const int* in_sizes, int n_in,
                              void* d_out, int out_size, void* d_ws, size_t ws_size,
                              hipStream_t stream) {
    const float* in = (const float*)d_in[0];
    char* ws = (char*)d_ws;
    ull* TB        = (ull*)(ws + OFF_TB);
    ull* TC        = (ull*)(ws + OFF_TC);
    ull* TD        = (ull*)(ws + OFF_TD);
    float4* boxes4 = (float4*)(ws + OFF_BOXES);
    float* scores  = (float*)(ws + OFF_SCORES);
    int* rank      = (int*)(ws + OFF_RANK);
    float* maxc    = (float*)(ws + OFF_MAXC);
    float* out     = (float*)d_out;

    k1_max_zero<<<32, 256, 0, stream>>>(in, (int*)maxc, rank);
    k2_rank<<<256, 256, 0, stream>>>(in, maxc, rank);
    k3_scatter<<<32, 256, 0, stream>>>(in, rank, maxc, boxes4, scores);
    k4_build<<<2176, 256, 0, stream>>>(boxes4, scores, TB, TC, TD);
    k5_nms<<<1, 1024, 0, stream>>>(boxes4, scores, TB, TC, TD, out);
}

// Round 14
// 131.152 us; speedup vs baseline: 1.1573x; 1.1573x over previous
//
#include <hip/hip_runtime.h>
#include <cstdint>

typedef unsigned long long ull;

#define N_BOX 8192
#define N_WORDS 128   // 8192 / 64
#define CH 512        // chunk size
#define WPC 8         // words per chunk

// ---------------- workspace layout ----------------
// TB (distance>=2 transposed col-blocks): 53760 rows * 64 B = 3,440,640 @ 0
// TC (superdiagonal transposed blocks):   15 * 32 KB        =   491,520 @ 3,440,640
// TD (per-chunk diagonal tables):         16 * 32 KB        =   524,288 @ 3,932,160
// boxes4 : 131072 @ 4,456,448
// scores : 32768  @ 4,587,520
// rank   : 32768  @ 4,620,288
// maxc   : 4      @ 4,653,056
#define OFF_TB     0
#define OFF_TC     3440640
#define OFF_TD     3932160
#define OFF_BOXES  4456448
#define OFF_SCORES 4587520
#define OFF_RANK   4620288
#define OFF_MAXC   4653056

// TB rows for source chunk c' cover j >= CH*(c'+2): 7168-512c' rows (c'=0..13)
__device__ __forceinline__ int rows_before2(int c) {
    return 7424 * c - 256 * c * c;   // sum_{c'<c} (7168 - 512c')
}

__device__ __forceinline__ ull make_key(float s, int idx) {
    // positive floats: bit pattern is order-preserving. Reversed index in the
    // low 13 bits reproduces stable argsort(-conf): equal conf -> lower index first.
    return (((ull)__float_as_uint(s)) << 13) | (ull)(8191 - idx);
}

__device__ __forceinline__ float box_area(float4 b) {
    return __fmul_rn(__fsub_rn(b.z, b.x), __fsub_rn(b.w, b.y));
}

// exact replica of reference IoU rounding (_rn ops block FMA contraction); symmetric.
__device__ __forceinline__ bool iou_gt_half(float4 a, float aarea, float4 b, float barea) {
    float ix1 = fmaxf(a.x, b.x);
    float iy1 = fmaxf(a.y, b.y);
    float ix2 = fminf(a.z, b.z);
    float iy2 = fminf(a.w, b.w);
    float iw = fmaxf(__fsub_rn(ix2, ix1), 0.0f);
    float ih = fmaxf(__fsub_rn(iy2, iy1), 0.0f);
    float inter = __fmul_rn(iw, ih);
    float uni = __fsub_rn(__fadd_rn(aarea, barea), inter);
    float iou = __fdiv_rn(inter, fmaxf(uni, 1e-9f));
    return iou > 0.5f;
}

// K1: global conf max via int-bits atomicMax (conf>=0; 0xAA.. poison is negative
// int so no pre-init needed); each block zeroes its rank slice.
__global__ __launch_bounds__(256) void k1_max_zero(const float* __restrict__ in,
                                                   int* __restrict__ maxci,
                                                   int* __restrict__ rank) {
    int t = threadIdx.x;
    int i = blockIdx.x * 256 + t;
    float c = in[i * 5 + 4];
    for (int off = 32; off; off >>= 1) c = fmaxf(c, __shfl_down(c, off));
    __shared__ float wm[4];
    if ((t & 63) == 0) wm[t >> 6] = c;
    __syncthreads();
    if (t == 0) {
        float m = fmaxf(fmaxf(wm[0], wm[1]), fmaxf(wm[2], wm[3]));
        atomicMax(maxci, __float_as_int(m));
    }
    rank[i] = 0;
}

// K2: rank[i] = #{ j : key_j > key_i }  (descending sort position, stable ties)
__global__ __launch_bounds__(256) void k2_rank(const float* __restrict__ in,
                                               const float* __restrict__ maxc_p,
                                               int* __restrict__ rank) {
    __shared__ ull keys[1024];
    int t = threadIdx.x;
    int bx = blockIdx.x;
    int it = bx & 31;       // i tile: 256 boxes
    int jt = bx >> 5;       // j tile: 1024 boxes (8 tiles)
    float maxc = *maxc_p;
    for (int r = 0; r < 4; ++r) {
        int j = jt * 1024 + r * 256 + t;
        float s = __fdiv_rn(in[j * 5 + 4], maxc);
        keys[r * 256 + t] = make_key(s, j);
    }
    __syncthreads();
    int i = it * 256 + t;
    ull ki = make_key(__fdiv_rn(in[i * 5 + 4], maxc), i);
    int cnt = 0;
    #pragma unroll 8
    for (int k = 0; k < 1024; ++k) cnt += (keys[k] > ki) ? 1 : 0;
    atomicAdd(&rank[i], cnt);
}

// K3: scatter boxes/scores into sorted order
__global__ __launch_bounds__(256) void k3_scatter(const float* __restrict__ in,
                                                  const int* __restrict__ rank,
                                                  const float* __restrict__ maxc_p,
                                                  float4* __restrict__ boxes4,
                                                  float* __restrict__ scores) {
    int i = blockIdx.x * 256 + threadIdx.x;
    float cx = in[i * 5 + 0];
    float cy = in[i * 5 + 1];
    float w  = in[i * 5 + 2];
    float h  = in[i * 5 + 3];
    float c  = in[i * 5 + 4];
    float maxc = *maxc_p;
    float s = __fdiv_rn(c, maxc);
    int r = rank[i];
    float4 b;
    b.x = __fsub_rn(cx, __fmul_rn(w, 0.5f));
    b.y = __fsub_rn(cy, __fmul_rn(h, 0.5f));
    b.z = __fadd_rn(cx, __fmul_rn(w, 0.5f));
    b.w = __fadd_rn(cy, __fmul_rn(h, 0.5f));
    boxes4[r] = b;
    scores[r] = s;
}

// K4: build suppression bit tables.
//  bid <  1680        : TB — source chunk c, target j >= CH*(c+2), 32 j x 8 w tiles
//  1680 <= bid < 1920 : TC — source chunk c (0..14), target chunk c+1; transposed
//                       TC[c][w][jl] = word-w boxes of chunk c suppressing jl
//  bid >= 1920        : TD — diagonal, TD[c][w][jl], pre-masked to suppressors < jl
__global__ __launch_bounds__(256) void k4_build(const float4* __restrict__ boxes4,
                                                const float* __restrict__ scores,
                                                ull* __restrict__ TB,
                                                ull* __restrict__ TC,
                                                ull* __restrict__ TD) {
    __shared__ float4 sb[CH];
    __shared__ float sa[CH];
    int bid = blockIdx.x;
    int t = threadIdx.x;
    int c;
    int mode;   // 0=TB, 1=TC, 2=TD
    int j0;     // TB: global j tile start; TC/TD: local jl tile start
    if (bid >= 1920) {
        mode = 2;
        int d = bid - 1920;
        c = d >> 4;
        j0 = (d & 15) * 32;
    } else if (bid >= 1680) {
        mode = 1;
        int d = bid - 1680;
        c = d >> 4;          // 0..14
        j0 = (d & 15) * 32;
    } else {
        mode = 0;
        c = 0;
        int rem = bid;
        while (rem >= 224 - 16 * c) { rem -= 224 - 16 * c; ++c; }
        j0 = CH * (c + 2) + rem * 32;
    }
    if (scores[c * CH] < 0.5f) return;               // source chunk never a suppressor
    if (mode == 0 && scores[j0] < 0.5f) return;      // j-tile never alive (desc scores)

    for (int i = t; i < CH; i += 256) {
        float4 b = boxes4[c * CH + i];
        sb[i] = b;
        sa[i] = box_area(b);
    }
    __syncthreads();

    int w = t & 7;
    int r = t >> 3;          // 0..31 local row
    if (mode == 2) {
        int jl = j0 + r;
        float4 me = sb[jl];
        float ma = sa[jl];
        int wj = jl >> 6;
        int lim = (w < wj) ? 64 : ((w == wj) ? (jl & 63) : 0);
        ull bits = 0;
        for (int k = 0; k < lim; ++k)
            if (iou_gt_half(sb[w * 64 + k], sa[w * 64 + k], me, ma)) bits |= 1ull << k;
        TD[c * 4096 + w * 512 + jl] = bits;
    } else if (mode == 1) {
        int jl = j0 + r;
        int j = CH * (c + 1) + jl;
        float4 me = boxes4[j];
        float ma = box_area(me);
        ull bits = 0;
        for (int k = 0; k < 64; ++k)
            if (iou_gt_half(sb[w * 64 + k], sa[w * 64 + k], me, ma)) bits |= 1ull << k;
        TC[c * 4096 + w * 512 + jl] = bits;
    } else {
        int j = j0 + r;
        float4 me = boxes4[j];
        float ma = box_area(me);
        ull bits = 0;
        for (int k = 0; k < 64; ++k)
            if (iou_gt_half(sb[w * 64 + k], sa[w * 64 + k], me, ma)) bits |= 1ull << k;
        TB[(size_t)(rows_before2(c) + (j - CH * (c + 2))) * WPC + w] = bits;
    }
}

// K5: chunk-sequential greedy NMS, one 1024-thread block, ONE barrier per chunk.
// R11 structure (best measured: 43.2 us). Only change vs R11: prefetch and
// chunk-0 staging use 16-byte ulonglong2 loads (fewer dependent load->ds_write
// iterations; R12/R13's split/quad variants regressed and are reverted).
//  Wave 0     : TC-ballot apply of kept[c-1] -> chunk c, then scan chunk c.
//  Waves 1-7  : deferred TB apply of kept[c-1] -> chunks >= c+1, two-phase
//               (LDS-only alive bitmask, then paired row loads).
//  Waves 8-15 : prefetch TD[c+1] + TC[c] jointly (2 vector loads in flight/iter).
__global__ __launch_bounds__(1024) void k5_nms(const float4* __restrict__ boxes4,
                                               const float* __restrict__ scores,
                                               const ull* __restrict__ TBg,
                                               const ull* __restrict__ TCg,
                                               const ull* __restrict__ TDg,
                                               float* __restrict__ out) {
    __shared__ ull TDb[2][CH * WPC];            // 2 x 32 KB
    __shared__ ull TCb[2][CH * WPC];            // 2 x 32 KB
    __shared__ unsigned amask32[2 * N_WORDS];
    __shared__ ull keptbuf[2][WPC];
    __shared__ int svb;
    int t = threadIdx.x;
    int lane = t & 63;
    int wave = t >> 6;

    // ---- vb from sorted-score prefix ----
    if (t == 0) svb = 0;
    __syncthreads();
    {
        int cnt = 0;
        #pragma unroll
        for (int k = 0; k < 8; ++k) cnt += (scores[k * 1024 + t] >= 0.5f) ? 1 : 0;
        for (int off = 32; off; off >>= 1) cnt += __shfl_down(cnt, off);
        if (lane == 0) atomicAdd(&svb, cnt);
    }
    // ---- stage chunk-0 TD (16B vector loads) while the add settles ----
    {
        const ulonglong2* src = (const ulonglong2*)TDg;
        ulonglong2* dst = (ulonglong2*)TDb[0];
        #pragma unroll
        for (int i2 = t; i2 < CH * WPC / 2; i2 += 1024) dst[i2] = src[i2];
    }
    if (t < WPC) { keptbuf[0][t] = 0; keptbuf[1][t] = 0; }
    __syncthreads();
    int vb = svb;

    // ---- alive mask from prefix ----
    if (t < 2 * N_WORDS) {
        int n = vb - t * 32;
        amask32[t] = (n >= 32) ? 0xffffffffu : ((n <= 0) ? 0u : ((1u << n) - 1u));
    }
    __syncthreads();

    int nchv = (vb + CH - 1) / CH;
    for (int c = 0; c < nchv; ++c) {
        int cur = c & 1;
        if (wave == 0) {
            // ---- load alive words of chunk c ----
            ull alive[WPC];
            #pragma unroll
            for (int w = 0; w < WPC; ++w)
                alive[w] = (ull)amask32[c * 16 + 2 * w] |
                           ((ull)amask32[c * 16 + 2 * w + 1] << 32);
            // ---- TC-ballot apply: kept[c-1] -> chunk c ----
            if (c > 0) {
                const ull* kb = keptbuf[(c - 1) & 1];
                const ull* TCc = TCb[cur];
                #pragma unroll
                for (int w = 0; w < WPC; ++w) {
                    ull kw = kb[w];
                    if (!kw) continue;
                    ull Tc2[WPC];
                    #pragma unroll
                    for (int v = 0; v < WPC; ++v)
                        Tc2[v] = TCc[w * 512 + v * 64 + lane];   // pipelined preload
                    #pragma unroll
                    for (int v = 0; v < WPC; ++v)
                        alive[v] &= ~__ballot((Tc2[v] & kw) != 0);
                }
            }
            // ---- scan chunk c (TD-col preload -> ballot fixpoint -> applies) ----
            const ull* T = TDb[cur];
            #pragma unroll
            for (int w = 0; w < WPC; ++w) {
                ull word = alive[w];
                if (!word) continue;
                ull Tc[WPC];
                #pragma unroll
                for (int j = 0; j < WPC; ++j)
                    if (j >= w) Tc[j] = T[w * 512 + j * 64 + lane];
                ull td = Tc[w];
                ull a2 = word, kept = 0;
                while (a2 & ~kept) {
                    bool al = (a2 >> lane) & 1;
                    bool kp = (kept >> lane) & 1;
                    ull nk = __ballot(al && !kp && ((td & a2) == 0));
                    ull nd = __ballot(al && !kp && ((td & kept) != 0));
                    kept |= nk;
                    a2 &= ~nd;
                }
                alive[w] = kept;
                #pragma unroll
                for (int j = 0; j < WPC; ++j) {
                    if (j <= w) continue;
                    if (!alive[j]) continue;
                    alive[j] &= ~__ballot((Tc[j] & kept) != 0);
                }
            }
            if (lane == 0) {
                #pragma unroll
                for (int w = 0; w < WPC; ++w) {
                    amask32[c * 16 + 2 * w]     = (unsigned)alive[w];
                    amask32[c * 16 + 2 * w + 1] = (unsigned)(alive[w] >> 32);
                    keptbuf[c & 1][w] = alive[w];
                }
            }
        } else if (wave < 8) {
            // ---- deferred TB apply: kept[c-1] -> j in chunks >= c+1 ----
            if (c > 0 && c - 1 <= 13) {
                const ull* kb = keptbuf[(c - 1) & 1];
                ull kw[WPC];
                ull anyk = 0;
                #pragma unroll
                for (int k = 0; k < WPC; ++k) { kw[k] = kb[k]; anyk |= kw[k]; }
                if (anyk) {
                    const ull* TBc = TBg + (size_t)rows_before2(c - 1) * WPC;
                    int jbase = CH * (c + 1);    // TB rows of chunk c-1 start here
                    int base = jbase + (t - 64);
                    // phase 1: LDS-only alive scan -> bitmask (pipelined reads)
                    unsigned am = 0;
                    int k = 0;
                    for (int j = base; j < vb; j += 448, ++k)
                        am |= (((amask32[j >> 5] >> (j & 31)) & 1u) << k);
                    // phase 2: paired row loads (2 rows in flight)
                    while (am) {
                        int b1 = __builtin_ctz(am);
                        am &= am - 1;
                        bool had2 = (am != 0);
                        int b2 = had2 ? __builtin_ctz(am) : b1;
                        if (had2) am &= am - 1;
                        int j1 = base + b1 * 448;
                        int j2 = base + b2 * 448;
                        const ull* r1 = TBc + (size_t)(j1 - jbase) * WPC;
                        const ull* r2 = TBc + (size_t)(j2 - jbase) * WPC;
                        ull a1 = 0, a2v = 0;
                        #pragma unroll
                        for (int q = 0; q < WPC; ++q) a1 |= r1[q] & kw[q];
                        #pragma unroll
                        for (int q = 0; q < WPC; ++q) a2v |= r2[q] & kw[q];
                        if (a1) atomicAnd(&amask32[j1 >> 5], ~(1u << (j1 & 31)));
                        if (had2 && a2v) atomicAnd(&amask32[j2 >> 5], ~(1u << (j2 & 31)));
                    }
                }
            }
        } else {
            // ---- prefetch TD[c+1] and TC[c] jointly (16B vector loads) ----
            if (c + 1 < nchv) {
                const ulonglong2* tdsrc = (const ulonglong2*)(TDg + (c + 1) * CH * WPC);
                const ulonglong2* tcsrc = (const ulonglong2*)(TCg + c * CH * WPC);
                ulonglong2* tddst = (ulonglong2*)TDb[cur ^ 1];
                ulonglong2* tcdst = (ulonglong2*)TCb[cur ^ 1];
                #pragma unroll
                for (int i2 = t - 512; i2 < CH * WPC / 2; i2 += 512) {
                    tddst[i2] = tdsrc[i2];
                    tcdst[i2] = tcsrc[i2];
                }
            }
        }
        __syncthreads();
    }

    // ---- epilogue: write all 8192 output rows ----
    #pragma unroll
    for (int rr = 0; rr < 8; ++rr) {
        int j = t * 8 + rr;
        bool kept = (amask32[j >> 5] >> (j & 31)) & 1u;
        float4 b = boxes4[j];
        float s = scores[j];
        out[j * 5 + 0] = kept ? b.x : 0.0f;
        out[j * 5 + 1] = kept ? b.y : 0.0f;
        out[j * 5 + 2] = kept ? b.z : 0.0f;
        out[j * 5 + 3] = kept ? b.w : 0.0f;
        out[j * 5 + 4] = kept ? s   : 0.0f;
    }
}

extern "C" void kernel_launch(void* const* d_in, const int* in_sizes, int n_in,
                              void* d_out, int out_size, void* d_ws, size_t ws_size,
                              hipStream_t stream) {
    const float* in = (const float*)d_in[0];
    char* ws = (char*)d_ws;
    ull* TB        = (ull*)(ws + OFF_TB);
    ull* TC        = (ull*)(ws + OFF_TC);
    ull* TD        = (ull*)(ws + OFF_TD);
    float4* boxes4 = (float4*)(ws + OFF_BOXES);
    float* scores  = (float*)(ws + OFF_SCORES);
    int* rank      = (int*)(ws + OFF_RANK);
    float* maxc    = (float*)(ws + OFF_MAXC);
    float* out     = (float*)d_out;

    k1_max_zero<<<32, 256, 0, stream>>>(in, (int*)maxc, rank);
    k2_rank<<<256, 256, 0, stream>>>(in, maxc, rank);
    k3_scatter<<<32, 256, 0, stream>>>(in, rank, maxc, boxes4, scores);
    k4_build<<<2176, 256, 0, stream>>>(boxes4, scores, TB, TC, TD);
    k5_nms<<<1, 1024, 0, stream>>>(boxes4, scores, TB, TC, TD, out);
}